// Round 5
// baseline (220.340 us; speedup 1.0000x reference)
//
#include <hip/hip_runtime.h>
#include <cmath>

#define BB 32
#define SS 2048
#define IND 300
#define HID 16
#define LAT 16
#define NA 64
#define NITER 20
#define GRAV 0.01f

// d_out layout (floats): field[32*16] | rec[32*2048*300] | masses[32] | change[1]
#define OFF_FIELD 0
#define OFF_REC   512
#define OFF_MASS  (512 + BB*SS*IND)
#define OFF_CHG   (OFF_MASS + BB)

// d_ws layout (floats)
#define WS_FIELD 0      // 512 accumulators
#define WS_CHG   512    // 64 spread accumulators for change

typedef __attribute__((ext_vector_type(8))) __bf16 bf16x8;
typedef __attribute__((ext_vector_type(4))) __bf16 bf16x4;
typedef __attribute__((ext_vector_type(2))) __bf16 bf16x2;
typedef __attribute__((ext_vector_type(4))) float f32x4;
typedef __attribute__((ext_vector_type(4))) unsigned uint4v;

#define HST 40   // h row stride (bf16): 80 B

__device__ __forceinline__ unsigned pk_bf16(float lo, float hi) {
    bf16x2 t; t[0] = (__bf16)lo; t[1] = (__bf16)hi;
    return __builtin_bit_cast(unsigned, t);
}

// ---------------------------------------------------------------------------
// Kernel 1: encoder only (fetch-phase; memory-bound). 16 tok/wave, 1024 blocks.
// p staged to pbuf (d_out rec region, overwritten later by k_bcast).
// ---------------------------------------------------------------------------
__global__ __launch_bounds__(256, 4)
void k_enc(const float* __restrict__ x,  const float* __restrict__ w1,
           const float* __restrict__ b1, const float* __restrict__ w2,
           const float* __restrict__ b2, float* __restrict__ pbuf)
{
    __shared__ __align__(16) __bf16 hl[4][16 * HST];   // 5120 B

    const int tid  = threadIdx.x;
    const int wave = tid >> 6, lane = tid & 63;
    const int quad = lane >> 4, col = lane & 15;
    const int tok  = blockIdx.x * 64 + wave * 16 + col;

    const float* xr = x + (size_t)tok * IND;
    f32x4 xv[10][2];
    #pragma unroll
    for (int s = 0; s < 9; ++s) {
        const float* xp = xr + s * 32 + quad * 8;
        xv[s][0] = *(const f32x4*)(xp);
        xv[s][1] = *(const f32x4*)(xp + 4);
    }
    {   // s = 9 tail: k = 288 + quad*8 + j; in-bounds loads only
        const f32x4 z = {0.f, 0.f, 0.f, 0.f};
        xv[9][0] = z; xv[9][1] = z;
        if (quad == 0) {
            xv[9][0] = *(const f32x4*)(xr + 288);
            xv[9][1] = *(const f32x4*)(xr + 292);
        } else if (quad == 1) {
            xv[9][0] = *(const f32x4*)(xr + 296);   // ends exactly at row end
        }
    }

    const float b1c = b1[col];
    f32x4 hacc = {b1c, b1c, b1c, b1c};
    #pragma unroll
    for (int s = 0; s < 10; ++s) {
        bf16x8 af, wf;
        #pragma unroll
        for (int e = 0; e < 4; ++e) {
            af[e]     = (__bf16)xv[s][0][e];
            af[4 + e] = (__bf16)xv[s][1][e];
        }
        if (s < 9) {
            #pragma unroll
            for (int j = 0; j < 8; ++j)
                wf[j] = (__bf16)w1[(s * 32 + quad * 8 + j) * HID + col];
        } else {
            #pragma unroll
            for (int j = 0; j < 8; ++j)
                wf[j] = (quad * 8 + j < 12)
                      ? (__bf16)w1[(288 + quad * 8 + j) * HID + col]
                      : (__bf16)0.f;
        }
        hacc = __builtin_amdgcn_mfma_f32_16x16x32_bf16(af, wf, hacc, 0, 0, 0);
    }

    __bf16* myh = hl[wave];
    #pragma unroll
    for (int r = 0; r < 4; ++r)
        myh[(quad * 4 + r) * HST + col] = (__bf16)fmaxf(hacc[r], 0.f);

    bf16x8 w2tf;
    #pragma unroll
    for (int j = 0; j < 8; ++j) {
        const int k = quad * 8 + j;
        w2tf[j] = (k < HID) ? (__bf16)w2[k * LAT + col] : (__bf16)0.f;
    }
    bf16x8 bh;
    #pragma unroll
    for (int e = 0; e < 8; ++e) bh[e] = (__bf16)0.f;
    if (quad < 2)
        bh = *(const bf16x8*)(myh + col * HST + quad * 8);
    f32x4 pacc = *(const f32x4*)(b2 + quad * 4);
    f32x4 p = __builtin_amdgcn_mfma_f32_16x16x32_bf16(w2tf, bh, pacc, 0, 0, 0);

    ((f32x4*)pbuf)[(size_t)tok * 4 + quad] = p;
}

// ---------------------------------------------------------------------------
// Kernel 2: gravity at 8 tokens/wave (cols 8-15 duplicate 0-7; exact 2x in
// the reduction, scaled by 0.5). 2048 blocks -> 8192 waves = 8 waves/SIMD
// (launch_bounds(256,8) caps VGPR at 64; sanvP folded into MFMA C operand).
// Shuffle-free permuted-attractor loop verbatim from r4 (harness-verified).
// ---------------------------------------------------------------------------
__global__ __launch_bounds__(256, 8)
void k_grav(const float* __restrict__ att, const float* __restrict__ pbuf,
            float* __restrict__ ws)
{
    __shared__ float red[4][LAT];
    __shared__ float redc[4];

    const int tid  = threadIdx.x;
    const int wave = tid >> 6, lane = tid & 63;
    const int quad = lane >> 4, col = lane & 15;
    const int tok  = blockIdx.x * 32 + wave * 8 + (col & 7);   // col>=8 duplicates

    f32x4 p = ((const f32x4*)pbuf)[(size_t)tok * 4 + quad];

    bf16x8 ones8;
    #pragma unroll
    for (int e = 0; e < 8; ++e) ones8[e] = (__bf16)1.0f;

    // aS[i]: A[m=col][k]: attractor g(i,col), k even -> -2*att[g][quad*4+k/2],
    // odd -> 1.   g(i,m) = 32*(i>>1) + 8*(m>>2) + 4*(i&1) + (m&3)
    bf16x8 aS[4];
    #pragma unroll
    for (int i = 0; i < 4; ++i) {
        const int arow = 32 * (i >> 1) + 8 * (col >> 2) + 4 * (i & 1) + (col & 3);
        f32x4 av = *(const f32x4*)(att + arow * LAT + quad * 4);
        #pragma unroll
        for (int m = 0; m < 4; ++m) {
            aS[i][2 * m]     = (__bf16)(-2.0f * av[m]);
            aS[i][2 * m + 1] = (__bf16)1.0f;
        }
    }
    // sanvP[i][r] = |att[g(i, 4*quad + r)]|^2 (same permutation as aS rows)
    f32x4 sanvP[4];
    {
        float nrm[4];
        #pragma unroll
        for (int i0 = 0; i0 < 4; ++i0) {
            const float* ar = att + (16 * i0 + col) * LAT;
            float s = 0.f;
            #pragma unroll
            for (int k = 0; k < LAT; ++k) s = fmaf(ar[k], ar[k], s);
            nrm[i0] = s;
        }
        float nrmSel[2];
        nrmSel[0] = (quad & 2) ? nrm[1] : nrm[0];
        nrmSel[1] = (quad & 2) ? nrm[3] : nrm[2];
        #pragma unroll
        for (int i = 0; i < 4; ++i)
            #pragma unroll
            for (int r = 0; r < 4; ++r) {
                const int src = (quad << 4) | (8 * (quad & 1) + 4 * (i & 1) + r);
                sanvP[i][r] = __shfl(nrmSel[i >> 1], src);
            }
    }
    // aF[h]: A[m=d=col][k = 32h + 8*quad + j]  (matches bw's k-order)
    bf16x8 aF[2];
    #pragma unroll
    for (int h = 0; h < 2; ++h)
        #pragma unroll
        for (int j = 0; j < 8; ++j)
            aF[h][j] = (__bf16)att[(32 * h + quad * 8 + j) * LAT + col];

    const f32x4 zf = {0.f, 0.f, 0.f, 0.f};
    float cd = 0.f;
    #pragma unroll 1
    for (int it = 0; it < NITER; ++it) {
        bf16x8 bp;                       // B[k][n=col]: k even -> p_d, odd -> p_d^2
        #pragma unroll
        for (int m = 0; m < 4; ++m) {
            float v = p[m];
            bp[2 * m]     = (__bf16)v;
            bp[2 * m + 1] = (__bf16)(v * v);
        }
        // sf = |a|^2 - 2 a.p + |p|^2  (sanvP folded in via C operand)
        f32x4 sf[4];
        #pragma unroll
        for (int i = 0; i < 4; ++i)
            sf[i] = __builtin_amdgcn_mfma_f32_16x16x32_bf16(aS[i], bp, sanvP[i], 0, 0, 0);

        float w[4][4];
        #pragma unroll
        for (int i = 0; i < 4; ++i)
            #pragma unroll
            for (int r = 0; r < 4; ++r)
                w[i][r] = __builtin_amdgcn_rcpf(sf[i][r]);

        uint4v u0 = { pk_bf16(w[0][0], w[0][1]), pk_bf16(w[0][2], w[0][3]),
                      pk_bf16(w[1][0], w[1][1]), pk_bf16(w[1][2], w[1][3]) };
        uint4v u1 = { pk_bf16(w[2][0], w[2][1]), pk_bf16(w[2][2], w[2][3]),
                      pk_bf16(w[3][0], w[3][1]), pk_bf16(w[3][2], w[3][3]) };
        bf16x8 bw0 = __builtin_bit_cast(bf16x8, u0);
        bf16x8 bw1 = __builtin_bit_cast(bf16x8, u1);

        f32x4 F  = __builtin_amdgcn_mfma_f32_16x16x32_bf16(aF[0], bw0, zf, 0, 0, 0);
        F  = __builtin_amdgcn_mfma_f32_16x16x32_bf16(aF[1], bw1, F,  0, 0, 0);
        f32x4 F2 = __builtin_amdgcn_mfma_f32_16x16x32_bf16(ones8, bw0, zf, 0, 0, 0);
        F2 = __builtin_amdgcn_mfma_f32_16x16x32_bf16(ones8, bw1, F2, 0, 0, 0);

        const bool last = (it == NITER - 1);
        #pragma unroll
        for (int r = 0; r < 4; ++r) {
            float np = fmaf(p[r], fmaf(F2[r], -0.1f * GRAV, 1.0f),
                            (0.1f * GRAV) * F[r]);
            if (last) { float d = np - p[r]; cd = fmaf(d, d, cd); }
            p[r] = np;
        }
    }

    // ---------------- reduction (duplicates -> exact 2x, scale 0.5) --------
    f32x4 fs = p;
    #pragma unroll
    for (int m = 1; m <= 8; m <<= 1)
        #pragma unroll
        for (int r = 0; r < 4; ++r) fs[r] += __shfl_xor(fs[r], m);
    if (col == 0) {
        #pragma unroll
        for (int r = 0; r < 4; ++r) red[wave][quad * 4 + r] = 0.5f * fs[r];
    }
    float c2 = cd;
    c2 += __shfl_xor(c2, 1);  c2 += __shfl_xor(c2, 2);  c2 += __shfl_xor(c2, 4);
    c2 += __shfl_xor(c2, 8);  c2 += __shfl_xor(c2, 16); c2 += __shfl_xor(c2, 32);
    if (lane == 0) redc[wave] = 0.5f * c2;
    __syncthreads();

    const int b = blockIdx.x >> 6;   // 64 blocks (32 tokens each) per batch row
    if (tid < LAT) {
        float v = red[0][tid] + red[1][tid] + red[2][tid] + red[3][tid];
        atomicAdd(ws + WS_FIELD + b * LAT + tid, v);
    }
    if (tid == 32)
        atomicAdd(ws + WS_CHG + (blockIdx.x & 63),
                  redc[0] + redc[1] + redc[2] + redc[3]);
}

// ---------------------------------------------------------------------------
// Fused finalize + broadcast (unchanged, harness-verified).
// ---------------------------------------------------------------------------
#define CHUNK 8192
#define CPB   (SS * IND / CHUNK)    // 75
__global__ __launch_bounds__(256)
void k_bcast(const float* __restrict__ dw1, const float* __restrict__ db1,
             const float* __restrict__ dw2, const float* __restrict__ db2,
             const float* __restrict__ mw,  const float* __restrict__ mb,
             const float* __restrict__ ws, float* __restrict__ out)
{
    __shared__ float sf[LAT];
    __shared__ float sh[HID];
    __shared__ float schg[64];
    __shared__ __align__(16) float srow[IND];
    const int blk = blockIdx.x;
    const int b = blk / CPB, c = blk % CPB;
    const int t = threadIdx.x;

    if (t < LAT) {
        float f = ws[WS_FIELD + b * LAT + t] * (1.f / SS);
        sf[t] = f;
        if (c == 0) out[OFF_FIELD + b * LAT + t] = f;
    }
    if (blk == 0 && t < 64) schg[t] = ws[WS_CHG + t];
    __syncthreads();
    if (t < HID) {
        float a = db1[t];
        #pragma unroll
        for (int d = 0; d < LAT; ++d) a = fmaf(sf[d], dw1[d * HID + t], a);
        sh[t] = fmaxf(a, 0.f);
    }
    if (c == 0 && t == 32) {
        float a = mb[0];
        #pragma unroll
        for (int d = 0; d < LAT; ++d) a = fmaf(sf[d], mw[d], a);
        out[OFF_MASS + b] = 1.f / (1.f + expf(-a));
    }
    if (blk == 0 && t == 33) {
        float s = 0.f;
        #pragma unroll
        for (int i = 0; i < 64; ++i) s += schg[i];
        out[OFF_CHG] = sqrtf(s);
    }
    __syncthreads();
    if (t < IND) {
        float a = db2[t];
        #pragma unroll
        for (int j = 0; j < HID; ++j) a = fmaf(sh[j], dw2[j * IND + t], a);
        srow[t] = a;
    }
    if (t < IND - 256) {
        const int tc = t + 256;
        float a2 = db2[tc];
        #pragma unroll
        for (int j = 0; j < HID; ++j) a2 = fmaf(sh[j], dw2[j * IND + tc], a2);
        srow[tc] = a2;
    }
    __syncthreads();
    f32x4* o = (f32x4*)(out + OFF_REC + (size_t)b * (SS * IND) + (size_t)c * CHUNK);
    #pragma unroll
    for (int i = 0; i < CHUNK / 4 / 256; ++i) {
        const int o4 = i * 256 + t;
        const int r  = (c * CHUNK + o4 * 4) % IND;   // r % 4 == 0
        f32x4 v = *(const f32x4*)(srow + r);
        __builtin_nontemporal_store(v, o + o4);
    }
}

extern "C" void kernel_launch(void* const* d_in, const int* in_sizes, int n_in,
                              void* d_out, int out_size, void* d_ws, size_t ws_size,
                              hipStream_t stream)
{
    const float* x   = (const float*)d_in[0];
    const float* ew1 = (const float*)d_in[1];
    const float* eb1 = (const float*)d_in[2];
    const float* ew2 = (const float*)d_in[3];
    const float* eb2 = (const float*)d_in[4];
    const float* att = (const float*)d_in[5];
    const float* dw1 = (const float*)d_in[6];
    const float* db1 = (const float*)d_in[7];
    const float* dw2 = (const float*)d_in[8];
    const float* db2 = (const float*)d_in[9];
    const float* mw  = (const float*)d_in[10];
    const float* mb  = (const float*)d_in[11];
    float* out = (float*)d_out;
    float* ws  = (float*)d_ws;
    float* pbuf = out + OFF_REC;   // 4 MB p staging in rec region (overwritten by k_bcast)

    (void)hipMemsetAsync(ws, 0, (WS_CHG + 64) * sizeof(float), stream);
    k_enc <<<BB * SS / 64,  256, 0, stream>>>(x, ew1, eb1, ew2, eb2, pbuf);
    k_grav<<<BB * SS / 32,  256, 0, stream>>>(att, pbuf, ws);
    k_bcast<<<BB * CPB, 256, 0, stream>>>(dw1, db1, dw2, db2, mw, mb, ws, out);
}

// Round 6
// 190.962 us; speedup vs baseline: 1.1538x; 1.1538x over previous
//
#include <hip/hip_runtime.h>
#include <cmath>

#define BB 32
#define SS 2048
#define IND 300
#define HID 16
#define LAT 16
#define NA 64
#define NITER 20
#define GRAV 0.01f

// d_out layout (floats): field[32*16] | rec[32*2048*300] | masses[32] | change[1]
#define OFF_FIELD 0
#define OFF_REC   512
#define OFF_MASS  (512 + BB*SS*IND)
#define OFF_CHG   (OFF_MASS + BB)

// d_ws layout (floats)
#define WS_FIELD 0      // 512 accumulators
#define WS_CHG   512    // 64 spread accumulators for change

typedef __attribute__((ext_vector_type(8))) __bf16 bf16x8;
typedef __attribute__((ext_vector_type(4))) __bf16 bf16x4;
typedef __attribute__((ext_vector_type(2))) __bf16 bf16x2;
typedef __attribute__((ext_vector_type(4))) float f32x4;
typedef __attribute__((ext_vector_type(4))) unsigned uint4v;

#define HST 40   // h row stride (bf16): 80 B

__device__ __forceinline__ unsigned pk_bf16(float lo, float hi) {
    bf16x2 t; t[0] = (__bf16)lo; t[1] = (__bf16)hi;
    return __builtin_bit_cast(unsigned, t);
}

// ---------------------------------------------------------------------------
// Kernel 1: encoder only (fetch-phase; memory-bound). 16 tok/wave, 1024 blocks.
// p staged to pbuf (d_out rec region, overwritten later by k_bcast). Verified r5.
// ---------------------------------------------------------------------------
__global__ __launch_bounds__(256, 4)
void k_enc(const float* __restrict__ x,  const float* __restrict__ w1,
           const float* __restrict__ b1, const float* __restrict__ w2,
           const float* __restrict__ b2, float* __restrict__ pbuf)
{
    __shared__ __align__(16) __bf16 hl[4][16 * HST];   // 5120 B

    const int tid  = threadIdx.x;
    const int wave = tid >> 6, lane = tid & 63;
    const int quad = lane >> 4, col = lane & 15;
    const int tok  = blockIdx.x * 64 + wave * 16 + col;

    const float* xr = x + (size_t)tok * IND;
    f32x4 xv[10][2];
    #pragma unroll
    for (int s = 0; s < 9; ++s) {
        const float* xp = xr + s * 32 + quad * 8;
        xv[s][0] = *(const f32x4*)(xp);
        xv[s][1] = *(const f32x4*)(xp + 4);
    }
    {   // s = 9 tail: k = 288 + quad*8 + j; in-bounds loads only
        const f32x4 z = {0.f, 0.f, 0.f, 0.f};
        xv[9][0] = z; xv[9][1] = z;
        if (quad == 0) {
            xv[9][0] = *(const f32x4*)(xr + 288);
            xv[9][1] = *(const f32x4*)(xr + 292);
        } else if (quad == 1) {
            xv[9][0] = *(const f32x4*)(xr + 296);   // ends exactly at row end
        }
    }

    const float b1c = b1[col];
    f32x4 hacc = {b1c, b1c, b1c, b1c};
    #pragma unroll
    for (int s = 0; s < 10; ++s) {
        bf16x8 af, wf;
        #pragma unroll
        for (int e = 0; e < 4; ++e) {
            af[e]     = (__bf16)xv[s][0][e];
            af[4 + e] = (__bf16)xv[s][1][e];
        }
        if (s < 9) {
            #pragma unroll
            for (int j = 0; j < 8; ++j)
                wf[j] = (__bf16)w1[(s * 32 + quad * 8 + j) * HID + col];
        } else {
            #pragma unroll
            for (int j = 0; j < 8; ++j)
                wf[j] = (quad * 8 + j < 12)
                      ? (__bf16)w1[(288 + quad * 8 + j) * HID + col]
                      : (__bf16)0.f;
        }
        hacc = __builtin_amdgcn_mfma_f32_16x16x32_bf16(af, wf, hacc, 0, 0, 0);
    }

    __bf16* myh = hl[wave];
    #pragma unroll
    for (int r = 0; r < 4; ++r)
        myh[(quad * 4 + r) * HST + col] = (__bf16)fmaxf(hacc[r], 0.f);

    bf16x8 w2tf;
    #pragma unroll
    for (int j = 0; j < 8; ++j) {
        const int k = quad * 8 + j;
        w2tf[j] = (k < HID) ? (__bf16)w2[k * LAT + col] : (__bf16)0.f;
    }
    bf16x8 bh;
    #pragma unroll
    for (int e = 0; e < 8; ++e) bh[e] = (__bf16)0.f;
    if (quad < 2)
        bh = *(const bf16x8*)(myh + col * HST + quad * 8);
    f32x4 pacc = *(const f32x4*)(b2 + quad * 4);
    f32x4 p = __builtin_amdgcn_mfma_f32_16x16x32_bf16(w2tf, bh, pacc, 0, 0, 0);

    ((f32x4*)pbuf)[(size_t)tok * 4 + quad] = p;
}

// ---------------------------------------------------------------------------
// Kernel 2: gravity, 16 tok/wave, 1024 blocks, (256,4) — the no-spill config.
// SINGLE CHANGE vs r4 gravity: quad-batched reciprocal (4 rcp + 36 mul per
// iter instead of 16 rcp) to offload the transcendental pipe.
// ---------------------------------------------------------------------------
__global__ __launch_bounds__(256, 4)
void k_grav(const float* __restrict__ att, const float* __restrict__ pbuf,
            float* __restrict__ ws)
{
    __shared__ float red[4][LAT];
    __shared__ float redc[4];

    const int tid  = threadIdx.x;
    const int wave = tid >> 6, lane = tid & 63;
    const int quad = lane >> 4, col = lane & 15;
    const int tok  = blockIdx.x * 64 + wave * 16 + col;

    f32x4 p = ((const f32x4*)pbuf)[(size_t)tok * 4 + quad];

    bf16x8 ones8;
    #pragma unroll
    for (int e = 0; e < 8; ++e) ones8[e] = (__bf16)1.0f;

    // aS[i]: A[m=col][k]: attractor g(i,col), k even -> -2*att[g][quad*4+k/2],
    // odd -> 1.   g(i,m) = 32*(i>>1) + 8*(m>>2) + 4*(i&1) + (m&3)
    bf16x8 aS[4];
    #pragma unroll
    for (int i = 0; i < 4; ++i) {
        const int arow = 32 * (i >> 1) + 8 * (col >> 2) + 4 * (i & 1) + (col & 3);
        f32x4 av = *(const f32x4*)(att + arow * LAT + quad * 4);
        #pragma unroll
        for (int m = 0; m < 4; ++m) {
            aS[i][2 * m]     = (__bf16)(-2.0f * av[m]);
            aS[i][2 * m + 1] = (__bf16)1.0f;
        }
    }
    // sanvP[i][r] = |att[g(i, 4*quad + r)]|^2 (same permutation as aS rows)
    f32x4 sanvP[4];
    {
        float nrm[4];
        #pragma unroll
        for (int i0 = 0; i0 < 4; ++i0) {
            const float* ar = att + (16 * i0 + col) * LAT;
            float s = 0.f;
            #pragma unroll
            for (int k = 0; k < LAT; ++k) s = fmaf(ar[k], ar[k], s);
            nrm[i0] = s;
        }
        float nrmSel[2];
        nrmSel[0] = (quad & 2) ? nrm[1] : nrm[0];
        nrmSel[1] = (quad & 2) ? nrm[3] : nrm[2];
        #pragma unroll
        for (int i = 0; i < 4; ++i)
            #pragma unroll
            for (int r = 0; r < 4; ++r) {
                const int src = (quad << 4) | (8 * (quad & 1) + 4 * (i & 1) + r);
                sanvP[i][r] = __shfl(nrmSel[i >> 1], src);
            }
    }
    // aF[h]: A[m=d=col][k = 32h + 8*quad + j]  (matches bw's k-order)
    bf16x8 aF[2];
    #pragma unroll
    for (int h = 0; h < 2; ++h)
        #pragma unroll
        for (int j = 0; j < 8; ++j)
            aF[h][j] = (__bf16)att[(32 * h + quad * 8 + j) * LAT + col];

    const f32x4 zf = {0.f, 0.f, 0.f, 0.f};
    float cd = 0.f;
    #pragma unroll 1
    for (int it = 0; it < NITER; ++it) {
        bf16x8 bp;                       // B[k][n=col]: k even -> p_d, odd -> p_d^2
        #pragma unroll
        for (int m = 0; m < 4; ++m) {
            float v = p[m];
            bp[2 * m]     = (__bf16)v;
            bp[2 * m + 1] = (__bf16)(v * v);
        }
        // sf = |a|^2 - 2 a.p + |p|^2  (sanvP folded in via C operand)
        f32x4 sf[4];
        #pragma unroll
        for (int i = 0; i < 4; ++i)
            sf[i] = __builtin_amdgcn_mfma_f32_16x16x32_bf16(aS[i], bp, sanvP[i], 0, 0, 0);

        // Quad-batched reciprocal: 1 rcp + 9 mul per 4 values (was 4 rcp).
        // W_k = partial products x rcp(S0*S1*S2*S3); rel err ~3e-7 << bf16 ulp.
        float w[4][4];
        #pragma unroll
        for (int i = 0; i < 4; ++i) {
            const float S0 = sf[i][0], S1 = sf[i][1], S2 = sf[i][2], S3 = sf[i][3];
            const float t01 = S0 * S1;
            const float t23 = S2 * S3;
            const float r   = __builtin_amdgcn_rcpf(t01 * t23);
            const float r01 = r * t23;
            const float r23 = r * t01;
            w[i][0] = r01 * S1;
            w[i][1] = r01 * S0;
            w[i][2] = r23 * S3;
            w[i][3] = r23 * S2;
        }

        uint4v u0 = { pk_bf16(w[0][0], w[0][1]), pk_bf16(w[0][2], w[0][3]),
                      pk_bf16(w[1][0], w[1][1]), pk_bf16(w[1][2], w[1][3]) };
        uint4v u1 = { pk_bf16(w[2][0], w[2][1]), pk_bf16(w[2][2], w[2][3]),
                      pk_bf16(w[3][0], w[3][1]), pk_bf16(w[3][2], w[3][3]) };
        bf16x8 bw0 = __builtin_bit_cast(bf16x8, u0);
        bf16x8 bw1 = __builtin_bit_cast(bf16x8, u1);

        f32x4 F  = __builtin_amdgcn_mfma_f32_16x16x32_bf16(aF[0], bw0, zf, 0, 0, 0);
        F  = __builtin_amdgcn_mfma_f32_16x16x32_bf16(aF[1], bw1, F,  0, 0, 0);
        f32x4 F2 = __builtin_amdgcn_mfma_f32_16x16x32_bf16(ones8, bw0, zf, 0, 0, 0);
        F2 = __builtin_amdgcn_mfma_f32_16x16x32_bf16(ones8, bw1, F2, 0, 0, 0);

        const bool last = (it == NITER - 1);
        #pragma unroll
        for (int r = 0; r < 4; ++r) {
            float np = fmaf(p[r], fmaf(F2[r], -0.1f * GRAV, 1.0f),
                            (0.1f * GRAV) * F[r]);
            if (last) { float d = np - p[r]; cd = fmaf(d, d, cd); }
            p[r] = np;
        }
    }

    // ---------------- reduction: wave -> block -> atomics ----------------
    f32x4 fs = p;
    #pragma unroll
    for (int m = 1; m <= 8; m <<= 1)
        #pragma unroll
        for (int r = 0; r < 4; ++r) fs[r] += __shfl_xor(fs[r], m);
    if (col == 0) {
        #pragma unroll
        for (int r = 0; r < 4; ++r) red[wave][quad * 4 + r] = fs[r];
    }
    float c2 = cd;
    c2 += __shfl_xor(c2, 1);  c2 += __shfl_xor(c2, 2);  c2 += __shfl_xor(c2, 4);
    c2 += __shfl_xor(c2, 8);  c2 += __shfl_xor(c2, 16); c2 += __shfl_xor(c2, 32);
    if (lane == 0) redc[wave] = c2;
    __syncthreads();

    const int b = blockIdx.x >> 5;   // 32 blocks (64 tokens each) per batch row
    if (tid < LAT) {
        float v = red[0][tid] + red[1][tid] + red[2][tid] + red[3][tid];
        atomicAdd(ws + WS_FIELD + b * LAT + tid, v);
    }
    if (tid == 32)
        atomicAdd(ws + WS_CHG + (blockIdx.x & 63),
                  redc[0] + redc[1] + redc[2] + redc[3]);
}

// ---------------------------------------------------------------------------
// Fused finalize + broadcast (unchanged, harness-verified).
// ---------------------------------------------------------------------------
#define CHUNK 8192
#define CPB   (SS * IND / CHUNK)    // 75
__global__ __launch_bounds__(256)
void k_bcast(const float* __restrict__ dw1, const float* __restrict__ db1,
             const float* __restrict__ dw2, const float* __restrict__ db2,
             const float* __restrict__ mw,  const float* __restrict__ mb,
             const float* __restrict__ ws, float* __restrict__ out)
{
    __shared__ float sf[LAT];
    __shared__ float sh[HID];
    __shared__ float schg[64];
    __shared__ __align__(16) float srow[IND];
    const int blk = blockIdx.x;
    const int b = blk / CPB, c = blk % CPB;
    const int t = threadIdx.x;

    if (t < LAT) {
        float f = ws[WS_FIELD + b * LAT + t] * (1.f / SS);
        sf[t] = f;
        if (c == 0) out[OFF_FIELD + b * LAT + t] = f;
    }
    if (blk == 0 && t < 64) schg[t] = ws[WS_CHG + t];
    __syncthreads();
    if (t < HID) {
        float a = db1[t];
        #pragma unroll
        for (int d = 0; d < LAT; ++d) a = fmaf(sf[d], dw1[d * HID + t], a);
        sh[t] = fmaxf(a, 0.f);
    }
    if (c == 0 && t == 32) {
        float a = mb[0];
        #pragma unroll
        for (int d = 0; d < LAT; ++d) a = fmaf(sf[d], mw[d], a);
        out[OFF_MASS + b] = 1.f / (1.f + expf(-a));
    }
    if (blk == 0 && t == 33) {
        float s = 0.f;
        #pragma unroll
        for (int i = 0; i < 64; ++i) s += schg[i];
        out[OFF_CHG] = sqrtf(s);
    }
    __syncthreads();
    if (t < IND) {
        float a = db2[t];
        #pragma unroll
        for (int j = 0; j < HID; ++j) a = fmaf(sh[j], dw2[j * IND + t], a);
        srow[t] = a;
    }
    if (t < IND - 256) {
        const int tc = t + 256;
        float a2 = db2[tc];
        #pragma unroll
        for (int j = 0; j < HID; ++j) a2 = fmaf(sh[j], dw2[j * IND + tc], a2);
        srow[tc] = a2;
    }
    __syncthreads();
    f32x4* o = (f32x4*)(out + OFF_REC + (size_t)b * (SS * IND) + (size_t)c * CHUNK);
    #pragma unroll
    for (int i = 0; i < CHUNK / 4 / 256; ++i) {
        const int o4 = i * 256 + t;
        const int r  = (c * CHUNK + o4 * 4) % IND;   // r % 4 == 0
        f32x4 v = *(const f32x4*)(srow + r);
        __builtin_nontemporal_store(v, o + o4);
    }
}

extern "C" void kernel_launch(void* const* d_in, const int* in_sizes, int n_in,
                              void* d_out, int out_size, void* d_ws, size_t ws_size,
                              hipStream_t stream)
{
    const float* x   = (const float*)d_in[0];
    const float* ew1 = (const float*)d_in[1];
    const float* eb1 = (const float*)d_in[2];
    const float* ew2 = (const float*)d_in[3];
    const float* eb2 = (const float*)d_in[4];
    const float* att = (const float*)d_in[5];
    const float* dw1 = (const float*)d_in[6];
    const float* db1 = (const float*)d_in[7];
    const float* dw2 = (const float*)d_in[8];
    const float* db2 = (const float*)d_in[9];
    const float* mw  = (const float*)d_in[10];
    const float* mb  = (const float*)d_in[11];
    float* out = (float*)d_out;
    float* ws  = (float*)d_ws;
    float* pbuf = out + OFF_REC;   // 4 MB p staging in rec region (overwritten by k_bcast)

    (void)hipMemsetAsync(ws, 0, (WS_CHG + 64) * sizeof(float), stream);
    k_enc <<<BB * SS / 64, 256, 0, stream>>>(x, ew1, eb1, ew2, eb2, pbuf);
    k_grav<<<BB * SS / 64, 256, 0, stream>>>(att, pbuf, ws);
    k_bcast<<<BB * CPB, 256, 0, stream>>>(dw1, db1, dw2, db2, mw, mb, ws, out);
}